// Round 3
// baseline (219.196 us; speedup 1.0000x reference)
//
#include <hip/hip_runtime.h>

#define Dm 128
#define Bn 16
#define TZ 8
#define TY 8
#define TX 16            // tile width in w; each thread owns a w-pair
#define HZ (TZ + 2)      // 10
#define HY (TY + 2)      // 10
#define HX (TX + 2)      // 18 valid columns
#define HXP 20           // padded LDS row stride: rows start at banks spaced by 4 -> conflict-free
#define TILE_N (HZ * HY * HXP)          // 2000
#define NT 512
#define NLOAD ((TILE_N + NT - 1) / NT)  // 4
#define VOX (Dm * Dm * Dm)
#define BCH 4            // batches per staged chunk
#define NCH (Bn / BCH)   // 4 chunks

__device__ __forceinline__ void gload_lds4(const void* g, void* l) {
  __builtin_amdgcn_global_load_lds(
      (const __attribute__((address_space(1))) void*)g,
      (__attribute__((address_space(3))) void*)l,
      4, 0, 0);
}

extern "C" __global__ void __launch_bounds__(512)
fused3d(const float* __restrict__ img, const float* __restrict__ x,
        const float* __restrict__ Wf, const float* __restrict__ bfp,
        float* __restrict__ out)
{
  __shared__ float sX[2][BCH][TILE_N];   // 64000 B

  const int tid = threadIdx.x;
  const int tx = tid & 7;          // w-pair index 0..7
  const int ty = (tid >> 3) & 7;   // h 0..7
  const int tz = tid >> 6;         // d 0..7 (== wave id)
  const int w0 = blockIdx.x * TX;
  const int h0 = blockIdx.y * TY;
  const int d0 = blockIdx.z * TZ;

  // ---- staging descriptors: LDS slot i <-> global voxel (same for every batch)
  int  goff[NLOAD];
  bool inb[NLOAD];
#pragma unroll
  for (int k = 0; k < NLOAD; ++k) {
    int i  = tid + k * NT;
    int r  = i / HXP;
    int c  = i - r * HXP;          // 0..19; c>=18 is pad
    int zz = r / HY;
    int yy = r - zz * HY;
    int gd = d0 + zz - 1;
    int gh = h0 + yy - 1;
    int gw = w0 + c - 1;
    inb[k]  = (i < TILE_N) & (c < HX) &
              ((unsigned)gd < Dm) & ((unsigned)gh < Dm) & ((unsigned)gw < Dm);
    goff[k] = (gd * Dm + gh) * Dm + gw;
  }

  // ---- zero-init both LDS buffers once: pad/OOB slots stay zero forever
  for (int i = tid; i < 2 * BCH * TILE_N; i += NT) ((float*)sX)[i] = 0.f;
  __syncthreads();

  const int wbase = tid & ~63;   // wave-uniform LDS base for global_load_lds

  // ---- stage chunk 0 (batches 0..3), async direct-to-LDS
#pragma unroll
  for (int j = 0; j < BCH; ++j) {
    const float* xb = x + (size_t)j * VOX;
#pragma unroll
    for (int k = 0; k < NLOAD; ++k)
      if (inb[k]) gload_lds4(xb + goff[k], &sX[0][j][k * NT + wbase]);
  }

  // ---- per-thread image window from GLOBAL (8 MB image is L3-resident):
  // 9 rows x 4 floats covering both w-pair voxels, edge-clamped to zero.
  float iw[9][4];
#pragma unroll
  for (int dz = 0; dz < 3; ++dz)
#pragma unroll
    for (int dy = 0; dy < 3; ++dy) {
      int gd = d0 + tz + dz - 1;
      int gh = h0 + ty + dy - 1;
      bool rowok = ((unsigned)gd < Dm) & ((unsigned)gh < Dm);
      const float* rp = img + ((size_t)gd * Dm + gh) * Dm;
      int rr = dz * 3 + dy;
#pragma unroll
      for (int c = 0; c < 4; ++c) {
        int gw = w0 + 2 * tx - 1 + c;
        iw[rr][c] = (rowok & ((unsigned)gw < Dm)) ? rp[gw] : 0.f;
      }
    }

  // ---- K[27] per voxel (pair); W,b are wave-uniform scalar loads
  float K0[27], K1[27];
#pragma unroll
  for (int o = 0; o < 27; ++o) {
    float a0 = bfp[o], a1 = bfp[o];
#pragma unroll
    for (int t = 0; t < 27; ++t) {
      float wv = Wf[o * 27 + t];
      int rr = t / 3, cc = t - rr * 3;
      a0 = fmaf(wv, iw[rr][cc],     a0);
      a1 = fmaf(wv, iw[rr][cc + 1], a1);
    }
    K0[o] = a0; K1[o] = a1;
  }

  __syncthreads();   // chunk 0 staged (vmcnt drained) & visible

  const int od = d0 + tz, oh = h0 + ty, ow = w0 + 2 * tx;
  const size_t obase = (((size_t)od) * Dm + oh) * Dm + ow;

  // ---- chunk loop: 4 chunks x 4 batches; one barrier per chunk
  for (int ch = 0; ch < NCH; ++ch) {
    const int cur = ch & 1;

    if (ch + 1 < NCH) {            // prefetch next chunk into other buffer
      const float* xc = x + (size_t)(ch + 1) * BCH * VOX;
#pragma unroll
      for (int j = 0; j < BCH; ++j) {
        const float* xb = xc + (size_t)j * VOX;
#pragma unroll
        for (int k = 0; k < NLOAD; ++k)
          if (inb[k]) gload_lds4(xb + goff[k], &sX[cur ^ 1][j][k * NT + wbase]);
      }
    }

#pragma unroll
    for (int j = 0; j < BCH; ++j) {
      const float* sxb = sX[cur][j];
      float acc0 = 0.f, acc1 = 0.f;
#pragma unroll
      for (int dz = 0; dz < 3; ++dz)
#pragma unroll
        for (int dy = 0; dy < 3; ++dy) {
          int base = ((tz + dz) * HY + (ty + dy)) * HXP + 2 * tx;
          float2 a  = *(const float2*)&sxb[base];
          float2 b2 = *(const float2*)&sxb[base + 2];
          int rr = dz * 3 + dy;
          acc0 = fmaf(K0[rr * 3 + 0], a.x,  acc0);
          acc0 = fmaf(K0[rr * 3 + 1], a.y,  acc0);
          acc0 = fmaf(K0[rr * 3 + 2], b2.x, acc0);
          acc1 = fmaf(K1[rr * 3 + 0], a.y,  acc1);
          acc1 = fmaf(K1[rr * 3 + 1], b2.x, acc1);
          acc1 = fmaf(K1[rr * 3 + 2], b2.y, acc1);
        }
      float2 st; st.x = acc0; st.y = acc1;
      *(float2*)&out[(size_t)(ch * BCH + j) * VOX + obase] = st;
    }

    __syncthreads();  // drains prefetch + guards buffer reuse
  }
}

extern "C" void kernel_launch(void* const* d_in, const int* in_sizes, int n_in,
                              void* d_out, int out_size, void* d_ws, size_t ws_size,
                              hipStream_t stream) {
  const float* img = (const float*)d_in[0];
  const float* x   = (const float*)d_in[1];
  const float* Wf  = (const float*)d_in[2];
  const float* bf  = (const float*)d_in[3];
  float* out = (float*)d_out;
  dim3 grid(Dm / TX, Dm / TY, Dm / TZ);  // 8 x 16 x 16 = 2048 blocks
  hipLaunchKernelGGL(fused3d, grid, dim3(NT), 0, stream, img, x, Wf, bf, out);
}